// Round 9
// baseline (103354.382 us; speedup 1.0000x reference)
//
#include <hip/hip_runtime.h>
#include <stdint.h>

typedef unsigned short u16;
typedef unsigned int   u32;
typedef _Float16 half2v __attribute__((ext_vector_type(2)));

#define L2E 1.4426950408889634f
#define TWO_L2E 2.8853900817779268f

__device__ __forceinline__ float bf2f(u16 b){ return __uint_as_float(((u32)b) << 16); }
__device__ __forceinline__ float ldf(const void* p, size_t i, int flag){
  return flag ? ((const float*)p)[i] : bf2f(((const u16*)p)[i]);
}
__device__ __forceinline__ float rcpfast(float x){
#if __has_builtin(__builtin_amdgcn_rcpf)
  return __builtin_amdgcn_rcpf(x);
#else
  return 1.0f / x;
#endif
}
__device__ __forceinline__ float exp2fast(float x){
#if __has_builtin(__builtin_amdgcn_exp2f)
  return __builtin_amdgcn_exp2f(x);
#else
  return exp2f(x);
#endif
}
__device__ __forceinline__ float fdot2f(u32 a, u32 b, float c){
#if __has_builtin(__builtin_amdgcn_fdot2)
  return __builtin_amdgcn_fdot2(__builtin_bit_cast(half2v, a), __builtin_bit_cast(half2v, b), c, false);
#else
  half2v ha = __builtin_bit_cast(half2v, a), hb = __builtin_bit_cast(half2v, b);
  return c + (float)ha[0]*(float)hb[0] + (float)ha[1]*(float)hb[1];
#endif
}
__device__ __forceinline__ u32 pkh2(float lo, float hi){
  half2v h; h[0] = (_Float16)lo; h[1] = (_Float16)hi;
  return __builtin_bit_cast(u32, h);
}
__device__ __forceinline__ u16 f2h16(float f){
  _Float16 h = (_Float16)f;
  return __builtin_bit_cast(u16, h);
}
__device__ __forceinline__ float h16f(u16 h){
  return (float)__builtin_bit_cast(_Float16, h);
}

// ---------------- sentinel / zero ----------------
__global__ void k_sentinelf(float* __restrict__ out, int n, float val){
  int i = blockIdx.x*256 + threadIdx.x;
  if(i < n) out[i] = val;
}
__global__ void k_zero(int* __restrict__ p, int n){
  int i = blockIdx.x*256 + threadIdx.x;
  if(i < n) p[i] = 0;
}

// ---------------- dtype detection + canonicalize ----------------
__global__ void k_detect(const u16* __restrict__ p, int n, int* __restrict__ flag){
  __shared__ int cnt;
  if(threadIdx.x == 0) cnt = 0;
  __syncthreads();
  int c = 0;
  for(int i = threadIdx.x; i < n; i += 256){
    int e = (p[i] >> 7) & 0xFF;
    c += (e >= 112 && e <= 142) ? 1 : 0;
  }
  atomicAdd(&cnt, c);
  __syncthreads();
  if(threadIdx.x == 0) *flag = (cnt >= (n/10)*9) ? 0 : 1;
}
__global__ void k_convf(const void* __restrict__ src, float* __restrict__ dst, int n,
                        const int* __restrict__ flag){
  int i = blockIdx.x*256 + threadIdx.x;
  if(i < n) dst[i] = ldf(src, i, *flag);
}

// ---------------- packs ----------------
// Wh2[d][k2][a] = fp16 pair (Wh[2k2][a], Wh[2k2+1][a])
__global__ void k_pack_wh2(const void* __restrict__ Wh, u32* __restrict__ out,
                           const int* __restrict__ flag){
  int i = blockIdx.x*256 + threadIdx.x;
  if(i >= 2*128*256) return;
  int d = i >> 15, k2 = (i >> 8) & 127, a = i & 255;
  float lo = ldf(Wh, ((size_t)d*256 + 2*k2    )*256 + a, *flag);
  float hi = ldf(Wh, ((size_t)d*256 + 2*k2 + 1)*256 + a, *flag);
  out[i] = pkh2(lo, hi);
}
// Wc3[d][w][k2][col], col = p*64+jjl, p<9; JJ = w*64+jjl
//   p<3: Whh[d][p*256+JJ][2k2..]; 3<=p<6: Wih[d][(p-3)*256+JJ][256+2k2..];
//   p>=6: Wih[d][(p-6)*256+JJ][2k2..]
__global__ void k_pack_wc3(const void* __restrict__ Whh, const void* __restrict__ Wih,
                           u32* __restrict__ out, const int* __restrict__ flag){
  int i = blockIdx.x*256 + threadIdx.x;
  if(i >= 2*4*128*576) return;
  int d  = i / 294912, r = i % 294912;
  int w  = r / 73728;  r %= 73728;
  int k2 = r / 576;
  int col = r % 576;
  int p = col >> 6, jjl = col & 63;
  int JJ = w*64 + jjl, k = 2*k2;
  float lo, hi;
  if(p < 3){
    size_t base = ((size_t)d*768 + p*256 + JJ)*256 + k;
    lo = ldf(Whh, base, *flag); hi = ldf(Whh, base + 1, *flag);
  } else if(p < 6){
    size_t base = ((size_t)d*768 + (p-3)*256 + JJ)*512 + 256 + k;
    lo = ldf(Wih, base, *flag); hi = ldf(Wih, base + 1, *flag);
  } else {
    size_t base = ((size_t)d*768 + (p-6)*256 + JJ)*512 + k;
    lo = ldf(Wih, base, *flag); hi = ldf(Wih, base + 1, *flag);
  }
  out[i] = pkh2(lo, hi);
}
// memh2 [32][512][128] u32 fp16-pairs
__global__ void k_pack_memh(const void* __restrict__ mem, u32* __restrict__ out, int n2,
                            const int* __restrict__ flag){
  int i = blockIdx.x*256 + threadIdx.x;
  if(i >= n2) return;
  out[i] = pkh2(ldf(mem, 2*(size_t)i, *flag), ldf(mem, 2*(size_t)i + 1, *flag));
}

// ---------------- GEMM C = A@B, fp16 u16 out (optional 2log2e scale) ----------------
template<int SCALE>
__global__ __launch_bounds__(256)
void k_gemm_h16(const float* __restrict__ A, int lda,
                const float* __restrict__ B, int ldb,
                u16* __restrict__ C, int N, int K)
{
  __shared__ float As[64][17];
  __shared__ float Bs[16][65];
  const int m0 = blockIdx.x * 64, n0 = blockIdx.y * 64;
  const int tid = threadIdx.x;
  const int arow = tid >> 2, acol = (tid & 3) * 4;
  const int brow = tid >> 4, bcol = (tid & 15) * 4;
  const int ty = tid >> 4, tx = tid & 15;
  float acc[4][4];
  #pragma unroll
  for(int i=0;i<4;++i)
    #pragma unroll
    for(int j=0;j<4;++j) acc[i][j] = 0.f;
  for(int k0 = 0; k0 < K; k0 += 16){
    float4 a4 = *(const float4*)(A + (size_t)(m0 + arow)*lda + k0 + acol);
    As[arow][acol+0] = a4.x; As[arow][acol+1] = a4.y;
    As[arow][acol+2] = a4.z; As[arow][acol+3] = a4.w;
    float4 b4 = *(const float4*)(B + (size_t)(k0 + brow)*ldb + n0 + bcol);
    Bs[brow][bcol+0] = b4.x; Bs[brow][bcol+1] = b4.y;
    Bs[brow][bcol+2] = b4.z; Bs[brow][bcol+3] = b4.w;
    __syncthreads();
    #pragma unroll
    for(int kk = 0; kk < 16; ++kk){
      float ar[4], br[4];
      #pragma unroll
      for(int i=0;i<4;++i) ar[i] = As[ty*4+i][kk];
      #pragma unroll
      for(int j=0;j<4;++j) br[j] = Bs[kk][tx*4+j];
      #pragma unroll
      for(int i=0;i<4;++i)
        #pragma unroll
        for(int j=0;j<4;++j) acc[i][j] = fmaf(ar[i], br[j], acc[i][j]);
    }
    __syncthreads();
  }
  #pragma unroll
  for(int i=0;i<4;++i)
    #pragma unroll
    for(int j=0;j<4;++j){
      float v = acc[i][j];
      if(SCALE) v *= TWO_L2E;
      C[(size_t)(m0 + ty*4 + i)*N + n0 + tx*4 + j] = f2h16(v);
    }
}

// ---------------- GEMM f32 out (for final G) ----------------
__global__ __launch_bounds__(256)
void k_gemm_f32(const float* __restrict__ A, int lda,
                const float* __restrict__ B, int ldb,
                float* __restrict__ C, int N, int K)
{
  __shared__ float As[64][17];
  __shared__ float Bs[16][65];
  const int m0 = blockIdx.x * 64, n0 = blockIdx.y * 64;
  const int tid = threadIdx.x;
  const int arow = tid >> 2, acol = (tid & 3) * 4;
  const int brow = tid >> 4, bcol = (tid & 15) * 4;
  const int ty = tid >> 4, tx = tid & 15;
  float acc[4][4];
  #pragma unroll
  for(int i=0;i<4;++i)
    #pragma unroll
    for(int j=0;j<4;++j) acc[i][j] = 0.f;
  for(int k0 = 0; k0 < K; k0 += 16){
    float4 a4 = *(const float4*)(A + (size_t)(m0 + arow)*lda + k0 + acol);
    As[arow][acol+0] = a4.x; As[arow][acol+1] = a4.y;
    As[arow][acol+2] = a4.z; As[arow][acol+3] = a4.w;
    float4 b4 = *(const float4*)(B + (size_t)(k0 + brow)*ldb + n0 + bcol);
    Bs[brow][bcol+0] = b4.x; Bs[brow][bcol+1] = b4.y;
    Bs[brow][bcol+2] = b4.z; Bs[brow][bcol+3] = b4.w;
    __syncthreads();
    #pragma unroll
    for(int kk = 0; kk < 16; ++kk){
      float ar[4], br[4];
      #pragma unroll
      for(int i=0;i<4;++i) ar[i] = As[ty*4+i][kk];
      #pragma unroll
      for(int j=0;j<4;++j) br[j] = Bs[kk][tx*4+j];
      #pragma unroll
      for(int i=0;i<4;++i)
        #pragma unroll
        for(int j=0;j<4;++j) acc[i][j] = fmaf(ar[i], br[j], acc[i][j]);
    }
    __syncthreads();
  }
  #pragma unroll
  for(int i=0;i<4;++i)
    #pragma unroll
    for(int j=0;j<4;++j)
      C[(size_t)(m0 + ty*4 + i)*N + n0 + tx*4 + j] = acc[i][j];
}

// ---------------- cooperative group barrier (4 WGs per chain) ----------------
__device__ __forceinline__ void groupbar(int* cntp, int target, int tid){
  __threadfence();
  __syncthreads();
  if(tid == 0){
    __hip_atomic_fetch_add(cntp, 1, __ATOMIC_RELEASE, __HIP_MEMORY_SCOPE_AGENT);
    long it = 0;
    while(__hip_atomic_load(cntp, __ATOMIC_ACQUIRE, __HIP_MEMORY_SCOPE_AGENT) < target
          && it < 2000000000L) ++it;
  }
  __syncthreads();
}

// ---------------- cooperative scan: 4 WGs per (dir,batch) chain ----------------
// LDS layout (bytes): Ptl 66560 | meml 66560 | spart 4096 | qv2 2048 | ghgi 2304 |
//                     h_l 1024 | v_l 1024 | es_l 512 | h2 512 | c2 512 | x2 512 | misc 64
#define SCAN_LDS 145728
__global__ __launch_bounds__(1024)
void k_scan3(const u16* __restrict__ Pt,     // [2][32][512][256] fp16 (pre-scaled 2log2e)
             const u16* __restrict__ qx16,   // [2][16384][256] fp16 (x@Wi)
             const u32* __restrict__ Wh2,    // [2][128][256] fp16 pairs
             const u32* __restrict__ Wc3,    // [2][4][128][576] fp16 pairs
             const float* __restrict__ xf,   // [32][512][256] f32
             const u32* __restrict__ memh2,  // [32][512][128] fp16 pairs
             const float* __restrict__ vf,
             const float* __restrict__ bihf,
             const float* __restrict__ bhhf,
             float* __restrict__ ys,         // [32][512][512] f32 = d_out
             float* __restrict__ cb,         // chain buffers: 64 × 2048 floats
             int* __restrict__ cnt)          // 64 × 16 ints
{
  extern __shared__ char smem[];
  u16*  Ptl   = (u16*)(smem);
  u16*  meml  = (u16*)(smem + 66560);
  float* spart = (float*)(smem + 133120);
  float2* qv2 = (float2*)(smem + 137216);
  float* ghgi = (float*)(smem + 139264);
  float* h_l  = (float*)(smem + 141568);
  float* v_l  = (float*)(smem + 142592);
  float* es_l = (float*)(smem + 143616);
  u32*  h2    = (u32*)(smem + 144128);
  u32*  c2    = (u32*)(smem + 144640);
  u32*  x2    = (u32*)(smem + 145152);
  float* misc = (float*)(smem + 145664);  // [0],[1]=esum wave partials; [2]=svp

  const int blk = blockIdx.x;
  const int c   = blk & 63;     // chain
  const int w   = blk >> 6;     // 0..3
  const int d   = c >> 5, b = c & 31;
  const int tid = threadIdx.x;
  const int lane = tid & 63, wave = tid >> 6;

  float* cbq = cb + (size_t)c*2048;        // q[256]
  float* cbe = cbq + 256;                  // esum[4]
  float* cbc = cbq + 512;                  // cpart[4][256]
  float* cbh = cbq + 1536;                 // hnew[256]
  int*   cntp = cnt + c*16;

  const u16* qxb = qx16 + ((size_t)d*16384 + (size_t)b*512)*256;
  const u32* Whd = Wh2 + (size_t)d*128*256;
  const u32* Wcd = Wc3 + ((size_t)(d*4 + w)*128)*576;
  const float* xb = xf + (size_t)b*512*256;

  // ---- preload P-slice and mem-slice into LDS (rows m-local 0..127) ----
  {
    const uint4* pg = (const uint4*)(Pt + (((size_t)(d*32 + b)*512 + w*128)*256));
    for(int idx = tid; idx < 4096; idx += 1024){
      int r = idx >> 5, s = idx & 31;         // 32 uint4 per 256-u16 row
      uint4 v = pg[(size_t)r*32 + s];
      u16* dst = Ptl + r*260 + s*8;
      *(uint2*)(dst)     = make_uint2(v.x, v.y);
      *(uint2*)(dst + 4) = make_uint2(v.z, v.w);
    }
    const uint4* mg = (const uint4*)(memh2 + (((size_t)b*512 + w*128)*128));
    for(int idx = tid; idx < 4096; idx += 1024){
      int r = idx >> 5, s = idx & 31;
      uint4 v = mg[(size_t)r*32 + s];
      u16* dst = meml + r*260 + s*8;
      *(uint2*)(dst)     = make_uint2(v.x, v.y);
      *(uint2*)(dst + 4) = make_uint2(v.z, v.w);
    }
  }
  if(tid < 256){ h_l[tid] = 0.f; v_l[tid] = vf[d*256 + tid]; }
  if(tid < 128) h2[tid] = 0u;
  __syncthreads();
  if(tid == 0){
    float s = 0.f;
    for(int i=0;i<256;++i) s += v_l[i];
    misc[2] = s * L2E;   // svp
  }
  // gate biases in regs (threads 0..63)
  float bh_r=0,bh_z=0,bh_n=0,bi_r=0,bi_z=0,bi_n=0;
  if(tid < 64){
    int JJ = w*64 + tid;
    bh_r = bhhf[d*768 + JJ];       bi_r = bihf[d*768 + JJ];
    bh_z = bhhf[d*768 + 256 + JJ]; bi_z = bihf[d*768 + 256 + JJ];
    bh_n = bhhf[d*768 + 512 + JJ]; bi_n = bihf[d*768 + 512 + JJ];
  }
  __syncthreads();

  for(int step = 0; step < 512; ++step){
    const int tx = d ? (511 - step) : step;
    const int tgt = 12*step;

    // S0: pack x2 (t<128) + R_Q partials (all threads: kq=tid>>6, al=tid&63)
    if(tid < 128){
      float2 xv = *(const float2*)(xb + (size_t)tx*256 + 2*tid);
      x2[tid] = pkh2(xv.x, xv.y);
    }
    {
      const int al = tid & 63, kq = tid >> 6;
      const u32* whp = Whd + (size_t)(kq*8)*256 + w*64 + al;
      float acc = 0.f;
      #pragma unroll
      for(int i=0;i<8;++i) acc = fdot2f(whp[(size_t)i*256], h2[kq*8 + i], acc);
      spart[kq*64 + al] = acc;
    }
    __syncthreads();
    // S1: q for a-slice -> cb
    if(tid < 64){
      float q = h16f(qxb[(size_t)tx*256 + w*64 + tid]);
      #pragma unroll
      for(int kq=0;kq<16;++kq) q += spart[kq*64 + tid];
      cbq[w*64 + tid] = q;
    }
    groupbar(cntp, tgt + 4, tid);

    // S2: rebuild qv2 (t<256)
    if(tid < 256) qv2[tid] = make_float2(TWO_L2E * cbq[tid], v_l[tid]);
    __syncthreads();

    // S3: R_A over m-slice: ml=tid&127, a-group g=tid>>7 (32 a each)
    {
      const int ml = tid & 127, g = tid >> 7;
      const u16* prow = Ptl + ml*260;
      float s0 = 0.f, s1 = 0.f;
      const float svdummy = 0.f; (void)svdummy;
      #pragma unroll 2
      for(int a0 = g*32; a0 < g*32 + 32; a0 += 4){
        uint2 pv = *(const uint2*)(prow + a0);
        half2v p01 = __builtin_bit_cast(half2v, pv.x);
        half2v p23 = __builtin_bit_cast(half2v, pv.y);
        float2 q0 = qv2[a0], q1 = qv2[a0+1], q2 = qv2[a0+2], q3 = qv2[a0+3];
        float e0 = exp2fast((float)p01[0] + q0.x);
        float e1 = exp2fast((float)p01[1] + q1.x);
        float e2 = exp2fast((float)p23[0] + q2.x);
        float e3 = exp2fast((float)p23[1] + q3.x);
        s0 = fmaf(q0.y, rcpfast(1.f + e0), s0);
        s1 = fmaf(q1.y, rcpfast(1.f + e1), s1);
        s0 = fmaf(q2.y, rcpfast(1.f + e2), s0);
        s1 = fmaf(q3.y, rcpfast(1.f + e3), s1);
      }
      spart[g*128 + ml] = s0 + s1;
    }
    __syncthreads();
    // S4: es per m-local (t<128), esum wave partials
    if(tid < 128){
      float s = 0.f;
      #pragma unroll
      for(int g=0; g<8; ++g) s += spart[g*128 + tid];
      float e = exp2fast(fmaf(-TWO_L2E, s, misc[2]));
      es_l[tid] = e;
      float es = e;
      #pragma unroll
      for(int off=1; off<64; off<<=1) es += __shfl_xor(es, off, 64);
      if(lane == 0) misc[wave] = es;
    }
    __syncthreads();
    // S5: Phase C partials over m-slice (t<256 = dm), esum store (t==0)
    if(tid < 256){
      float a0 = 0.f, a1 = 0.f;
      #pragma unroll 4
      for(int ml=0; ml<128; ml += 2){
        a0 = fmaf(h16f(meml[ml*260 + tid]),     es_l[ml],   a0);
        a1 = fmaf(h16f(meml[(ml+1)*260 + tid]), es_l[ml+1], a1);
      }
      cbc[w*256 + tid] = a0 + a1;
    }
    if(tid == 0) cbe[w] = misc[0] + misc[1];
    groupbar(cntp, tgt + 8, tid);

    // S6: combine c + pack c2 (t<128 handles 2 columns)
    if(tid < 128){
      float et = cbe[0] + cbe[1] + cbe[2] + cbe[3];
      float rs = rcpfast(et);
      float lo = (cbc[2*tid]       + cbc[256 + 2*tid]       + cbc[512 + 2*tid]       + cbc[768 + 2*tid])       * rs;
      float hi = (cbc[2*tid + 1]   + cbc[256 + 2*tid + 1]   + cbc[512 + 2*tid + 1]   + cbc[768 + 2*tid + 1])   * rs;
      c2[tid] = pkh2(lo, hi);
    }
    __syncthreads();

    // S7: R_G — 576 cols, 128 fdot2 each (4 accumulators)
    if(tid < 576){
      const int p = tid >> 6;
      const u32* src = (p < 3) ? h2 : ((p < 6) ? c2 : x2);
      const u32* wp = Wcd + tid;
      float a0=0.f, a1=0.f, a2=0.f, a3=0.f;
      #pragma unroll 4
      for(int k=0;k<32;++k){
        a0 = fdot2f(wp[(size_t)k*576],        src[k],     a0);
        a1 = fdot2f(wp[(size_t)(k+32)*576],   src[k+32],  a1);
        a2 = fdot2f(wp[(size_t)(k+64)*576],   src[k+64],  a2);
        a3 = fdot2f(wp[(size_t)(k+96)*576],   src[k+96],  a3);
      }
      ghgi[tid] = (a0+a1)+(a2+a3);
    }
    __syncthreads();
    // S8: gates for jj-slice (t<64), write hnew + ys
    if(tid < 64){
      const int JJ = w*64 + tid;
      float hr  = ghgi[0*64 + tid] + bh_r;
      float hz  = ghgi[1*64 + tid] + bh_z;
      float hn  = ghgi[2*64 + tid] + bh_n;
      float ir  = ghgi[3*64 + tid] + ghgi[6*64 + tid] + bi_r;
      float iz  = ghgi[4*64 + tid] + ghgi[7*64 + tid] + bi_z;
      float inn = ghgi[5*64 + tid] + ghgi[8*64 + tid] + bi_n;
      float r = rcpfast(1.f + exp2fast(-(ir + hr) * L2E));
      float z = rcpfast(1.f + exp2fast(-(iz + hz) * L2E));
      float narg = inn + r*hn;
      float n = 1.f - 2.f*rcpfast(1.f + exp2fast(narg * TWO_L2E));
      float hnew = (1.f - z)*n + z*h_l[JJ];
      cbh[JJ] = hnew;
      ys[((size_t)b*512 + tx)*512 + d*256 + JJ] = hnew;
    }
    groupbar(cntp, tgt + 12, tid);

    // S9: rebuild h + h2 (t<128 handles 2)
    if(tid < 128){
      float lo = cbh[2*tid], hi = cbh[2*tid + 1];
      h_l[2*tid] = lo; h_l[2*tid + 1] = hi;
      h2[tid] = pkh2(lo, hi);
    }
    __syncthreads();
  }
}

// ---------------- final gate: out = sigmoid(G) * ys, f32 in-place ----------------
__global__ void k_gate(const float* __restrict__ G, float* __restrict__ ysb, int n4){
  int i = blockIdx.x*256 + threadIdx.x;
  if(i >= n4) return;
  float4 g = ((const float4*)G)[i];
  float4 y = ((const float4*)ysb)[i];
  float4 o;
  o.x = y.x * rcpfast(1.f + exp2fast(-g.x * L2E));
  o.y = y.y * rcpfast(1.f + exp2fast(-g.y * L2E));
  o.z = y.z * rcpfast(1.f + exp2fast(-g.z * L2E));
  o.w = y.w * rcpfast(1.f + exp2fast(-g.w * L2E));
  ((float4*)ysb)[i] = o;
}

// ---------------- host ----------------
extern "C" void kernel_launch(void* const* d_in, const int* in_sizes, int n_in,
                              void* d_out, int out_size, void* d_ws, size_t ws_size,
                              hipStream_t stream)
{
  int iIn=-1, iMem=-1, iW[3]={-1,-1,-1}, nW=0, iV=-1, iWih=-1, iWhh=-1,
      iBih=-1, iBhh=-1, iWg=-1;
  for(int i = 0; i < n_in; ++i){
    switch(in_sizes[i]){
      case 4194304: if(iIn < 0) iIn = i; else if(iMem < 0) iMem = i; break;
      case 131072:  if(nW < 3) iW[nW++] = i; break;
      case 512:     iV = i; break;
      case 786432:  iWih = i; break;
      case 393216:  iWhh = i; break;
      case 1536:    if(iBih < 0) iBih = i; else if(iBhh < 0) iBhh = i; break;
      case 262144:  iWg = i; break;
      default: break;
    }
  }
  bool ok = (iIn>=0 && iMem>=0 && nW==3 && iV>=0 && iWih>=0 && iWhh>=0 &&
             iBih>=0 && iBhh>=0 && iWg>=0);
  if(!ok){
    k_sentinelf<<<(out_size + 255)/256, 256, 0, stream>>>((float*)d_out, out_size, 42.0f);
    return;
  }

  char* ws = (char*)d_ws;
  size_t off = 0;
  auto alloc = [&](size_t bytes)->void*{
    void* pp = ws + off; off += (bytes + 255) & ~(size_t)255; return pp;
  };
  float* cxf   = (float*)alloc(4194304ull*4);     // 16.8 MB (+cmemf = G after scan)
  float* cmemf = (float*)alloc(4194304ull*4);     // 16.8 MB
  u16*   Pt16  = (u16*)  alloc(2ull*16384*256*2); // 16.8 MB
  u16*   qx16  = (u16*)  alloc(2ull*16384*256*2); // 16.8 MB
  u32*   memh2 = (u32*)  alloc(32ull*512*128*4);  //  8.4 MB
  u32*   Wh2   = (u32*)  alloc(2ull*128*256*4);   //  0.26 MB
  u32*   Wc3   = (u32*)  alloc(2ull*4*128*576*4); //  2.36 MB
  float* Wmf   = (float*)alloc(131072ull*4);
  float* Wif   = (float*)alloc(131072ull*4);
  float* Wgf   = (float*)alloc(262144ull*4);
  float* cvf   = (float*)alloc(512ull*4);
  float* bihf  = (float*)alloc(1536ull*4);
  float* bhhf  = (float*)alloc(1536ull*4);
  float* cb    = (float*)alloc(64ull*2048*4);     //  0.52 MB chain share buffers
  int*   cnt   = (int*)  alloc(64ull*16*4);
  int*   flag  = (int*)  alloc(256);
  if(off > ws_size){
    k_sentinelf<<<(out_size + 255)/256, 256, 0, stream>>>((float*)d_out, out_size, 43.0f);
    return;
  }

  k_detect<<<1, 256, 0, stream>>>((const u16*)d_in[iIn], 65536, flag);

  auto conv = [&](const void* src, float* dst, int n){
    k_convf<<<(n + 255)/256, 256, 0, stream>>>(src, dst, n, flag);
  };
  conv(d_in[iIn],   cxf,   4194304);
  conv(d_in[iMem],  cmemf, 4194304);
  conv(d_in[iW[0]], Wmf,   131072);
  conv(d_in[iW[1]], Wif,   131072);
  conv(d_in[iV],    cvf,   512);
  conv(d_in[iBih],  bihf,  1536);
  conv(d_in[iBhh],  bhhf,  1536);
  conv(d_in[iWg],   Wgf,   262144);
  k_pack_wh2<<<(2*128*256 + 255)/256, 256, 0, stream>>>(d_in[iW[2]], Wh2, flag);
  k_pack_wc3<<<(2*4*128*576 + 255)/256, 256, 0, stream>>>(d_in[iWhh], d_in[iWih], Wc3, flag);
  k_pack_memh<<<(2097152 + 255)/256, 256, 0, stream>>>(d_in[iMem], memh2, 2097152, flag);

  // Pt16 = fp16( (memory@Wm[d]) * 2log2e ) ; qx16 = fp16( x@Wi[d] )
  for(int dd = 0; dd < 2; ++dd){
    k_gemm_h16<1><<<dim3(256, 4), 256, 0, stream>>>(
        cmemf, 256, Wmf + (size_t)dd*65536, 256,
        Pt16 + (size_t)dd*16384*256, 256, 256);
    k_gemm_h16<0><<<dim3(256, 4), 256, 0, stream>>>(
        cxf, 256, Wif + (size_t)dd*65536, 256,
        qx16 + (size_t)dd*16384*256, 256, 256);
  }

  // zero chain counters (per launch -> graph-replay safe)
  k_zero<<<4, 256, 0, stream>>>(cnt, 64*16);

  (void)hipFuncSetAttribute((const void*)k_scan3,
                            hipFuncAttributeMaxDynamicSharedMemorySize, SCAN_LDS);
  k_scan3<<<256, 1024, SCAN_LDS, stream>>>(Pt16, qx16, Wh2, Wc3, cxf, memh2,
                                           cvf, bihf, bhhf,
                                           (float*)d_out, cb, cnt);

  // G = ys@Wg (into cxf+cmemf, free after scan)
  float* G = cxf;
  k_gemm_f32<<<dim3(256, 8), 256, 0, stream>>>(
      (const float*)d_out, 512, Wgf, 512, G, 512, 512);
  k_gate<<<(8388608/4 + 255)/256, 256, 0, stream>>>(G, (float*)d_out, 8388608/4);
}

// Round 10
// 13672.865 us; speedup vs baseline: 7.5591x; 7.5591x over previous
//
#include <hip/hip_runtime.h>
#include <stdint.h>

typedef unsigned short u16;
typedef unsigned int   u32;
typedef _Float16 half2v __attribute__((ext_vector_type(2)));

#define L2E 1.4426950408889634f
#define TWO_L2E 2.8853900817779268f

__device__ __forceinline__ float bf2f(u16 b){ return __uint_as_float(((u32)b) << 16); }
__device__ __forceinline__ float ldf(const void* p, size_t i, int flag){
  return flag ? ((const float*)p)[i] : bf2f(((const u16*)p)[i]);
}
__device__ __forceinline__ float rcpfast(float x){
#if __has_builtin(__builtin_amdgcn_rcpf)
  return __builtin_amdgcn_rcpf(x);
#else
  return 1.0f / x;
#endif
}
__device__ __forceinline__ float exp2fast(float x){
#if __has_builtin(__builtin_amdgcn_exp2f)
  return __builtin_amdgcn_exp2f(x);
#else
  return exp2f(x);
#endif
}
__device__ __forceinline__ float fdot2f(u32 a, u32 b, float c){
#if __has_builtin(__builtin_amdgcn_fdot2)
  return __builtin_amdgcn_fdot2(__builtin_bit_cast(half2v, a), __builtin_bit_cast(half2v, b), c, false);
#else
  half2v ha = __builtin_bit_cast(half2v, a), hb = __builtin_bit_cast(half2v, b);
  return c + (float)ha[0]*(float)hb[0] + (float)ha[1]*(float)hb[1];
#endif
}
__device__ __forceinline__ u32 pkh2(float lo, float hi){
  half2v h; h[0] = (_Float16)lo; h[1] = (_Float16)hi;
  return __builtin_bit_cast(u32, h);
}
__device__ __forceinline__ u16 f2h16(float f){
  _Float16 h = (_Float16)f;
  return __builtin_bit_cast(u16, h);
}
__device__ __forceinline__ float h16f(u16 h){
  return (float)__builtin_bit_cast(_Float16, h);
}

// ---------------- sentinel ----------------
__global__ void k_sentinelf(float* __restrict__ out, int n, float val){
  int i = blockIdx.x*256 + threadIdx.x;
  if(i < n) out[i] = val;
}

// ---------------- dtype detection + canonicalize ----------------
__global__ void k_detect(const u16* __restrict__ p, int n, int* __restrict__ flag){
  __shared__ int cnt;
  if(threadIdx.x == 0) cnt = 0;
  __syncthreads();
  int c = 0;
  for(int i = threadIdx.x; i < n; i += 256){
    int e = (p[i] >> 7) & 0xFF;
    c += (e >= 112 && e <= 142) ? 1 : 0;
  }
  atomicAdd(&cnt, c);
  __syncthreads();
  if(threadIdx.x == 0) *flag = (cnt >= (n/10)*9) ? 0 : 1;
}
__global__ void k_convf(const void* __restrict__ src, float* __restrict__ dst, int n,
                        const int* __restrict__ flag){
  int i = blockIdx.x*256 + threadIdx.x;
  if(i < n) dst[i] = ldf(src, i, *flag);
}

// ---------------- packs ----------------
// Wh2[d][k2][a] = fp16 pair (Wh[2k2][a], Wh[2k2+1][a]), k2<128
__global__ void k_pack_wh2(const void* __restrict__ Wh, u32* __restrict__ out,
                           const int* __restrict__ flag){
  int i = blockIdx.x*256 + threadIdx.x;
  if(i >= 2*128*256) return;
  int d = i >> 15, k2 = (i >> 8) & 127, a = i & 255;
  float lo = ldf(Wh, ((size_t)d*256 + 2*k2    )*256 + a, *flag);
  float hi = ldf(Wh, ((size_t)d*256 + 2*k2 + 1)*256 + a, *flag);
  out[i] = pkh2(lo, hi);
}
// Wc2[d][k2][j], k2<128 (k=2k2,2k2+1), j<2304:
//   j<768: Whh[d][j][k]; 768..1536: Wih[d][j-768][256+k]; >=1536: Wih[d][j-1536][k]
__global__ void k_pack_wc2(const void* __restrict__ Whh, const void* __restrict__ Wih,
                           u32* __restrict__ out, const int* __restrict__ flag){
  int i = blockIdx.x*256 + threadIdx.x;
  if(i >= 2*128*2304) return;
  int d = i / (128*2304), r = i % (128*2304);
  int k2 = r / 2304, j = r % 2304;
  int k = 2*k2;
  float lo, hi;
  if(j < 768){
    lo = ldf(Whh, ((size_t)d*768 + j)*256 + k,     *flag);
    hi = ldf(Whh, ((size_t)d*768 + j)*256 + k + 1, *flag);
  } else if(j < 1536){
    lo = ldf(Wih, ((size_t)d*768 + (j-768))*512 + 256 + k,     *flag);
    hi = ldf(Wih, ((size_t)d*768 + (j-768))*512 + 256 + k + 1, *flag);
  } else {
    lo = ldf(Wih, ((size_t)d*768 + (j-1536))*512 + k,     *flag);
    hi = ldf(Wih, ((size_t)d*768 + (j-1536))*512 + k + 1, *flag);
  }
  out[i] = pkh2(lo, hi);
}
// generic fp16-pair pack of a float tensor (n2 = n/2 pairs)
__global__ void k_pack_h2(const void* __restrict__ src, u32* __restrict__ out, int n2,
                          const int* __restrict__ flag){
  int i = blockIdx.x*256 + threadIdx.x;
  if(i >= n2) return;
  out[i] = pkh2(ldf(src, 2*(size_t)i, *flag), ldf(src, 2*(size_t)i + 1, *flag));
}

// ---------------- GEMM C = A@B, fp16 out. MODE 0: plain; MODE 1: clamp(exp2(v*2log2e)) ----
template<int MODE>
__global__ __launch_bounds__(256)
void k_gemm_h16(const float* __restrict__ A, int lda,
                const float* __restrict__ B, int ldb,
                u16* __restrict__ C, int N, int K)
{
  __shared__ float As[64][17];
  __shared__ float Bs[16][65];
  const int m0 = blockIdx.x * 64, n0 = blockIdx.y * 64;
  const int tid = threadIdx.x;
  const int arow = tid >> 2, acol = (tid & 3) * 4;
  const int brow = tid >> 4, bcol = (tid & 15) * 4;
  const int ty = tid >> 4, tx = tid & 15;
  float acc[4][4];
  #pragma unroll
  for(int i=0;i<4;++i)
    #pragma unroll
    for(int j=0;j<4;++j) acc[i][j] = 0.f;
  for(int k0 = 0; k0 < K; k0 += 16){
    float4 a4 = *(const float4*)(A + (size_t)(m0 + arow)*lda + k0 + acol);
    As[arow][acol+0] = a4.x; As[arow][acol+1] = a4.y;
    As[arow][acol+2] = a4.z; As[arow][acol+3] = a4.w;
    float4 b4 = *(const float4*)(B + (size_t)(k0 + brow)*ldb + n0 + bcol);
    Bs[brow][bcol+0] = b4.x; Bs[brow][bcol+1] = b4.y;
    Bs[brow][bcol+2] = b4.z; Bs[brow][bcol+3] = b4.w;
    __syncthreads();
    #pragma unroll
    for(int kk = 0; kk < 16; ++kk){
      float ar[4], br[4];
      #pragma unroll
      for(int i=0;i<4;++i) ar[i] = As[ty*4+i][kk];
      #pragma unroll
      for(int j=0;j<4;++j) br[j] = Bs[kk][tx*4+j];
      #pragma unroll
      for(int i=0;i<4;++i)
        #pragma unroll
        for(int j=0;j<4;++j) acc[i][j] = fmaf(ar[i], br[j], acc[i][j]);
    }
    __syncthreads();
  }
  #pragma unroll
  for(int i=0;i<4;++i)
    #pragma unroll
    for(int j=0;j<4;++j){
      float v = acc[i][j];
      if(MODE==1){ v = exp2fast(v * TWO_L2E); v = fminf(v, 65504.f); }
      C[(size_t)(m0 + ty*4 + i)*N + n0 + tx*4 + j] = f2h16(v);
    }
}

// ---------------- recurrent scan v4: one WG per (dir,batch), E-trick + fused region ----
__global__ __launch_bounds__(1024)
void k_scan4(const u16* __restrict__ E16,    // [2][16384][256] fp16 e^{2P} clamped
             const u16* __restrict__ qx16,   // [2][16384][256] fp16 x@Wi
             const u32* __restrict__ Wh2,    // [2][128][256] fp16 pairs
             const u32* __restrict__ Wc2,    // [2][128][2304] fp16 pairs
             const u32* __restrict__ xh2,    // [32][512][128] fp16 pairs
             const u32* __restrict__ memh2,  // [32][512][128] fp16 pairs
             const float* __restrict__ vf,
             const float* __restrict__ bihf,
             const float* __restrict__ bhhf,
             float* __restrict__ ys)         // [32][512][512] f32 = d_out
{
  __shared__ float h_l[256];
  __shared__ u32 h2[128], c2[128], x2[128];
  __shared__ float F[256];
  __shared__ __align__(16) float part[4096];
  __shared__ float ghgi[2304];
  __shared__ float esum_w[16];
  __shared__ float svp_sh;

  const int tid = threadIdx.x;
  const int p = blockIdx.x, d = p >> 5, b = p & 31;
  const int lane = tid & 63, wave = tid >> 6;
  const int a4 = lane * 4;

  const u16* Eb  = E16  + ((size_t)d*16384 + (size_t)b*512)*256;
  const u16* qxb = qx16 + ((size_t)d*16384 + (size_t)b*512)*256;
  const u32* Whd = Wh2  + (size_t)d*128*256;
  const u32* Wcd = Wc2  + (size_t)d*128*2304;
  const u32* xhb = xh2  + (size_t)b*512*128;
  const u32* mhb = memh2+ (size_t)b*512*128;

  // ---- prologue
  if(tid < 256){ h_l[tid] = 0.f; part[tid] = vf[d*256 + tid]; }
  if(tid < 128){
    h2[tid] = 0u;
    int tx0 = d ? 511 : 0;
    x2[tid] = xhb[(size_t)tx0*128 + tid];
  }
  const float va0 = vf[d*256 + a4 + 0];
  const float va1 = vf[d*256 + a4 + 1];
  const float va2 = vf[d*256 + a4 + 2];
  const float va3 = vf[d*256 + a4 + 3];
  float bh0=0,bh1=0,bh2=0,bi0=0,bi1=0,bi2=0;
  if(tid < 256){
    bh0 = bhhf[d*768 + tid];       bi0 = bihf[d*768 + tid];
    bh1 = bhhf[d*768 + 256 + tid]; bi1 = bihf[d*768 + 256 + tid];
    bh2 = bhhf[d*768 + 512 + tid]; bi2 = bihf[d*768 + 512 + tid];
  }
  __syncthreads();
  if(tid == 0){ float s=0.f; for(int i=0;i<256;++i) s += part[i]; svp_sh = s * L2E; }
  __syncthreads();

  for(int step = 0; step < 512; ++step){
    const int tx = d ? (511 - step) : step;

    // S0: R_Q — q partials (h@Wh only; x-part precomputed). kq=tid>>8 (4×32 k2)
    {
      const int a = tid & 255, kq = tid >> 8;
      const u32* wp = Whd + (size_t)(kq*32)*256 + a;
      float q0 = 0.f, q1 = 0.f;
      #pragma unroll 8
      for(int i=0;i<16;++i){
        q0 = fdot2f(wp[(size_t)i*256],      h2[kq*32 + i],      q0);
        q1 = fdot2f(wp[(size_t)(i+16)*256], h2[kq*32 + i + 16], q1);
      }
      part[kq*256 + a] = q0 + q1;
    }
    __syncthreads();
    // S1: F = e^{2q} (f32)
    if(tid < 256){
      float q = h16f(qxb[(size_t)tx*256 + tid])
              + part[tid] + part[256+tid] + part[512+tid] + part[768+tid];
      F[tid] = exp2fast(q * TWO_L2E);
    }
    __syncthreads();

    // S2 REGION: gemv h/x-cols (stream-heavy) + R_A (VALU-heavy) — wave-skew overlap
    {
      // (a) 1536 cols not depending on c
      auto gdot = [&](int col, const u32* s2){
        const u32* wp = Wcd + col;
        float a0=0.f, a1=0.f, a2=0.f, a3=0.f;
        #pragma unroll 4
        for(int k=0;k<32;++k){
          a0 = fdot2f(wp[(size_t)k*2304],       s2[k],      a0);
          a1 = fdot2f(wp[(size_t)(k+32)*2304],  s2[k+32],   a1);
          a2 = fdot2f(wp[(size_t)(k+64)*2304],  s2[k+64],   a2);
          a3 = fdot2f(wp[(size_t)(k+96)*2304],  s2[k+96],   a3);
        }
        ghgi[col] = (a0+a1)+(a2+a3);
      };
      if(tid < 768) gdot(tid, h2);
      else          gdot(1536 + (tid - 768), x2);
      if(tid < 512) gdot(1792 + tid, x2);

      // (b) R_A: per wave 32 m-rows; per element fma(E,F)+rcp (no exp2)
      const float F0 = F[a4], F1 = F[a4+1], F2 = F[a4+2], F3 = F[a4+3];
      const float svp = svp_sh;
      float esum = 0.f, c0=0.f, c1=0.f, c2v=0.f, c3=0.f;
      #pragma unroll 2
      for(int i=0;i<32;++i){
        const int m = wave*32 + i;
        uint2 ev = *(const uint2*)(Eb + (size_t)m*256 + a4);
        half2v e01 = __builtin_bit_cast(half2v, ev.x);
        half2v e23 = __builtin_bit_cast(half2v, ev.y);
        float t0 = rcpfast(fmaf((float)e01[0], F0, 1.f));
        float t1 = rcpfast(fmaf((float)e01[1], F1, 1.f));
        float t2 = rcpfast(fmaf((float)e23[0], F2, 1.f));
        float t3 = rcpfast(fmaf((float)e23[1], F3, 1.f));
        float u = fmaf(va0, t0, fmaf(va1, t1, fmaf(va2, t2, va3*t3)));
        #pragma unroll
        for(int off=1; off<64; off<<=1) u += __shfl_xor(u, off, 64);
        float es = exp2fast(fmaf(u, -TWO_L2E, svp));   // e^{s_m}
        esum += es;
        uint2 mm = *(const uint2*)(mhb + (size_t)m*128 + lane*2);
        half2v ma = __builtin_bit_cast(half2v, mm.x);
        half2v mb2 = __builtin_bit_cast(half2v, mm.y);
        c0  = fmaf((float)ma[0],  es, c0);
        c1  = fmaf((float)ma[1],  es, c1);
        c2v = fmaf((float)mb2[0], es, c2v);
        c3  = fmaf((float)mb2[1], es, c3);
      }
      *(float4*)&part[wave*256 + a4] = make_float4(c0, c1, c2v, c3);
      if(lane == 0) esum_w[wave] = esum;
    }
    __syncthreads();

    // S3: combine c + pack c2 (tid<128, 2 columns each)
    if(tid < 128){
      float rs = 0.f;
      #pragma unroll
      for(int w=0; w<16; ++w) rs += esum_w[w];
      rs = rcpfast(rs);
      float lo = 0.f, hi = 0.f;
      #pragma unroll
      for(int w=0; w<16; ++w){
        lo += part[w*256 + 2*tid];
        hi += part[w*256 + 2*tid + 1];
      }
      c2[tid] = pkh2(lo*rs, hi*rs);
    }
    __syncthreads();

    // S4: gemv c-cols (768)
    if(tid < 768){
      const int col = 768 + tid;
      const u32* wp = Wcd + col;
      float a0=0.f, a1=0.f, a2=0.f, a3=0.f;
      #pragma unroll 4
      for(int k=0;k<32;++k){
        a0 = fdot2f(wp[(size_t)k*2304],       c2[k],      a0);
        a1 = fdot2f(wp[(size_t)(k+32)*2304],  c2[k+32],   a1);
        a2 = fdot2f(wp[(size_t)(k+64)*2304],  c2[k+64],   a2);
        a3 = fdot2f(wp[(size_t)(k+96)*2304],  c2[k+96],   a3);
      }
      ghgi[col] = (a0+a1)+(a2+a3);
    }
    __syncthreads();

    // S5: gates + h update
    if(tid < 256){
      const int j = tid;
      float hr  = ghgi[j]       + bh0;
      float hz  = ghgi[256 + j] + bh1;
      float hn  = ghgi[512 + j] + bh2;
      float ir  = ghgi[1536 + j]       + ghgi[768 + j]       + bi0;
      float iz  = ghgi[1536 + 256 + j] + ghgi[768 + 256 + j] + bi1;
      float inn = ghgi[1536 + 512 + j] + ghgi[768 + 512 + j] + bi2;
      float r = rcpfast(1.f + exp2fast(-(ir + hr) * L2E));
      float z = rcpfast(1.f + exp2fast(-(iz + hz) * L2E));
      float narg = inn + r*hn;
      float n = 1.f - 2.f*rcpfast(1.f + exp2fast(narg * TWO_L2E));
      float hnew = (1.f - z)*n + z*h_l[j];
      h_l[j] = hnew;
      ys[((size_t)b*512 + tx)*512 + d*256 + j] = hnew;
    }
    __syncthreads();

    // S6: pack h2 + next x2
    if(tid < 128){
      h2[tid] = pkh2(h_l[2*tid], h_l[2*tid + 1]);
    } else if(tid < 256 && step < 511){
      int t = tid - 128;
      int txn = d ? (511 - (step+1)) : (step+1);
      x2[t] = xhb[(size_t)txn*128 + t];
    }
    __syncthreads();
  }
}

// ---------------- final gate: out = sigmoid(G16) * ys, in place ----------------
__global__ void k_gate_h(const u16* __restrict__ G, float* __restrict__ ysb, int n4){
  int i = blockIdx.x*256 + threadIdx.x;
  if(i >= n4) return;
  ushort4 g = ((const ushort4*)G)[i];
  float4 y = ((const float4*)ysb)[i];
  float4 o;
  o.x = y.x * rcpfast(1.f + exp2fast(-h16f(g.x) * L2E));
  o.y = y.y * rcpfast(1.f + exp2fast(-h16f(g.y) * L2E));
  o.z = y.z * rcpfast(1.f + exp2fast(-h16f(g.z) * L2E));
  o.w = y.w * rcpfast(1.f + exp2fast(-h16f(g.w) * L2E));
  ((float4*)ysb)[i] = o;
}

// ---------------- host ----------------
extern "C" void kernel_launch(void* const* d_in, const int* in_sizes, int n_in,
                              void* d_out, int out_size, void* d_ws, size_t ws_size,
                              hipStream_t stream)
{
  int iIn=-1, iMem=-1, iW[3]={-1,-1,-1}, nW=0, iV=-1, iWih=-1, iWhh=-1,
      iBih=-1, iBhh=-1, iWg=-1;
  for(int i = 0; i < n_in; ++i){
    switch(in_sizes[i]){
      case 4194304: if(iIn < 0) iIn = i; else if(iMem < 0) iMem = i; break;
      case 131072:  if(nW < 3) iW[nW++] = i; break;
      case 512:     iV = i; break;
      case 786432:  iWih = i; break;
      case 393216:  iWhh = i; break;
      case 1536:    if(iBih < 0) iBih = i; else if(iBhh < 0) iBhh = i; break;
      case 262144:  iWg = i; break;
      default: break;
    }
  }
  bool ok = (iIn>=0 && iMem>=0 && nW==3 && iV>=0 && iWih>=0 && iWhh>=0 &&
             iBih>=0 && iBhh>=0 && iWg>=0);
  if(!ok){
    k_sentinelf<<<(out_size + 255)/256, 256, 0, stream>>>((float*)d_out, out_size, 42.0f);
    return;
  }

  char* ws = (char*)d_ws;
  size_t off = 0;
  auto alloc = [&](size_t bytes)->void*{
    void* pp = ws + off; off += (bytes + 255) & ~(size_t)255; return pp;
  };
  float* cxf   = (float*)alloc(4194304ull*4);     // 16.8 MB (G16 reuses after scan)
  float* cmemf = (float*)alloc(4194304ull*4);     // 16.8 MB
  u16*   E16   = (u16*)  alloc(2ull*16384*256*2); // 16.8 MB
  u16*   qx16  = (u16*)  alloc(2ull*16384*256*2); // 16.8 MB
  u32*   memh2 = (u32*)  alloc(32ull*512*128*4);  //  8.4 MB
  u32*   xh2   = (u32*)  alloc(32ull*512*128*4);  //  8.4 MB
  u32*   Wh2   = (u32*)  alloc(2ull*128*256*4);   //  0.26 MB
  u32*   Wc2   = (u32*)  alloc(2ull*128*2304*4);  //  2.36 MB
  float* Wmf   = (float*)alloc(131072ull*4);
  float* Wif   = (float*)alloc(131072ull*4);
  float* Wgf   = (float*)alloc(262144ull*4);
  float* cvf   = (float*)alloc(512ull*4);
  float* bihf  = (float*)alloc(1536ull*4);
  float* bhhf  = (float*)alloc(1536ull*4);
  int*   flag  = (int*)  alloc(256);
  if(off > ws_size){
    k_sentinelf<<<(out_size + 255)/256, 256, 0, stream>>>((float*)d_out, out_size, 43.0f);
    return;
  }

  k_detect<<<1, 256, 0, stream>>>((const u16*)d_in[iIn], 65536, flag);

  auto conv = [&](const void* src, float* dst, int n){
    k_convf<<<(n + 255)/256, 256, 0, stream>>>(src, dst, n, flag);
  };
  conv(d_in[iIn],   cxf,   4194304);
  conv(d_in[iMem],  cmemf, 4194304);
  conv(d_in[iW[0]], Wmf,   131072);
  conv(d_in[iW[1]], Wif,   131072);
  conv(d_in[iV],    cvf,   512);
  conv(d_in[iBih],  bihf,  1536);
  conv(d_in[iBhh],  bhhf,  1536);
  conv(d_in[iWg],   Wgf,   262144);
  k_pack_wh2<<<(2*128*256 + 255)/256, 256, 0, stream>>>(d_in[iW[2]], Wh2, flag);
  k_pack_wc2<<<(2*128*2304 + 255)/256, 256, 0, stream>>>(d_in[iWhh], d_in[iWih], Wc2, flag);
  k_pack_h2<<<(2097152 + 255)/256, 256, 0, stream>>>(d_in[iMem], memh2, 2097152, flag);
  k_pack_h2<<<(2097152 + 255)/256, 256, 0, stream>>>(d_in[iIn],  xh2,   2097152, flag);

  // E16 = clamp(e^{2·(mem@Wm)}) fp16 ; qx16 = fp16(x@Wi)
  for(int dd = 0; dd < 2; ++dd){
    k_gemm_h16<1><<<dim3(256, 4), 256, 0, stream>>>(
        cmemf, 256, Wmf + (size_t)dd*65536, 256,
        E16 + (size_t)dd*16384*256, 256, 256);
    k_gemm_h16<0><<<dim3(256, 4), 256, 0, stream>>>(
        cxf, 256, Wif + (size_t)dd*65536, 256,
        qx16 + (size_t)dd*16384*256, 256, 256);
  }

  // recurrent scan -> ys (f32) in d_out
  k_scan4<<<64, 1024, 0, stream>>>(E16, qx16, Wh2, Wc2, xh2, memh2,
                                   cvf, bihf, bhhf, (float*)d_out);

  // G16 = fp16(ys@Wg) into cxf space; gate in place
  u16* G16 = (u16*)cxf;
  k_gemm_h16<0><<<dim3(256, 8), 256, 0, stream>>>(
      (const float*)d_out, 512, Wgf, 512, G16, 512, 512);
  k_gate_h<<<(8388608/4 + 255)/256, 256, 0, stream>>>(G16, (float*)d_out, 8388608/4);
}

// Round 11
// 10187.320 us; speedup vs baseline: 10.1454x; 1.3421x over previous
//
#include <hip/hip_runtime.h>
#include <stdint.h>

typedef unsigned short u16;
typedef unsigned int   u32;
typedef _Float16 half2v __attribute__((ext_vector_type(2)));

#define L2E 1.4426950408889634f
#define TWO_L2E 2.8853900817779268f

__device__ __forceinline__ float bf2f(u16 b){ return __uint_as_float(((u32)b) << 16); }
__device__ __forceinline__ float ldf(const void* p, size_t i, int flag){
  return flag ? ((const float*)p)[i] : bf2f(((const u16*)p)[i]);
}
__device__ __forceinline__ float rcpfast(float x){
#if __has_builtin(__builtin_amdgcn_rcpf)
  return __builtin_amdgcn_rcpf(x);
#else
  return 1.0f / x;
#endif
}
__device__ __forceinline__ float exp2fast(float x){
#if __has_builtin(__builtin_amdgcn_exp2f)
  return __builtin_amdgcn_exp2f(x);
#else
  return exp2f(x);
#endif
}
__device__ __forceinline__ float fdot2f(u32 a, u32 b, float c){
#if __has_builtin(__builtin_amdgcn_fdot2)
  return __builtin_amdgcn_fdot2(__builtin_bit_cast(half2v, a), __builtin_bit_cast(half2v, b), c, false);
#else
  half2v ha = __builtin_bit_cast(half2v, a), hb = __builtin_bit_cast(half2v, b);
  return c + (float)ha[0]*(float)hb[0] + (float)ha[1]*(float)hb[1];
#endif
}
__device__ __forceinline__ u32 pkh2(float lo, float hi){
  half2v h; h[0] = (_Float16)lo; h[1] = (_Float16)hi;
  return __builtin_bit_cast(u32, h);
}
__device__ __forceinline__ u16 f2h16(float f){
  _Float16 h = (_Float16)f;
  return __builtin_bit_cast(u16, h);
}
__device__ __forceinline__ float h16f(u16 h){
  return (float)__builtin_bit_cast(_Float16, h);
}

// ---------------- sentinel ----------------
__global__ void k_sentinelf(float* __restrict__ out, int n, float val){
  int i = blockIdx.x*256 + threadIdx.x;
  if(i < n) out[i] = val;
}

// ---------------- dtype detection + canonicalize ----------------
__global__ void k_detect(const u16* __restrict__ p, int n, int* __restrict__ flag){
  __shared__ int cnt;
  if(threadIdx.x == 0) cnt = 0;
  __syncthreads();
  int c = 0;
  for(int i = threadIdx.x; i < n; i += 256){
    int e = (p[i] >> 7) & 0xFF;
    c += (e >= 112 && e <= 142) ? 1 : 0;
  }
  atomicAdd(&cnt, c);
  __syncthreads();
  if(threadIdx.x == 0) *flag = (cnt >= (n/10)*9) ? 0 : 1;
}
__global__ void k_convf(const void* __restrict__ src, float* __restrict__ dst, int n,
                        const int* __restrict__ flag){
  int i = blockIdx.x*256 + threadIdx.x;
  if(i < n) dst[i] = ldf(src, i, *flag);
}

// ---------------- packs ----------------
__global__ void k_pack_wh2(const void* __restrict__ Wh, u32* __restrict__ out,
                           const int* __restrict__ flag){
  int i = blockIdx.x*256 + threadIdx.x;
  if(i >= 2*128*256) return;
  int d = i >> 15, k2 = (i >> 8) & 127, a = i & 255;
  float lo = ldf(Wh, ((size_t)d*256 + 2*k2    )*256 + a, *flag);
  float hi = ldf(Wh, ((size_t)d*256 + 2*k2 + 1)*256 + a, *flag);
  out[i] = pkh2(lo, hi);
}
// Wc2[d][k2][j], j<2304: j<768: Whh[j][k]; 768..1536: Wih[j-768][256+k]; >=1536: Wih[j-1536][k]
__global__ void k_pack_wc2(const void* __restrict__ Whh, const void* __restrict__ Wih,
                           u32* __restrict__ out, const int* __restrict__ flag){
  int i = blockIdx.x*256 + threadIdx.x;
  if(i >= 2*128*2304) return;
  int d = i / (128*2304), r = i % (128*2304);
  int k2 = r / 2304, j = r % 2304;
  int k = 2*k2;
  float lo, hi;
  if(j < 768){
    lo = ldf(Whh, ((size_t)d*768 + j)*256 + k,     *flag);
    hi = ldf(Whh, ((size_t)d*768 + j)*256 + k + 1, *flag);
  } else if(j < 1536){
    lo = ldf(Wih, ((size_t)d*768 + (j-768))*512 + 256 + k,     *flag);
    hi = ldf(Wih, ((size_t)d*768 + (j-768))*512 + 256 + k + 1, *flag);
  } else {
    lo = ldf(Wih, ((size_t)d*768 + (j-1536))*512 + k,     *flag);
    hi = ldf(Wih, ((size_t)d*768 + (j-1536))*512 + k + 1, *flag);
  }
  out[i] = pkh2(lo, hi);
}
__global__ void k_pack_h2(const void* __restrict__ src, u32* __restrict__ out, int n2,
                          const int* __restrict__ flag){
  int i = blockIdx.x*256 + threadIdx.x;
  if(i >= n2) return;
  out[i] = pkh2(ldf(src, 2*(size_t)i, *flag), ldf(src, 2*(size_t)i + 1, *flag));
}
// WihT[d][k][j] = Wih[d][j][k]  (f32, x-part of W_ih)
__global__ void k_pack_wiht(const void* __restrict__ Wih, float* __restrict__ out,
                            const int* __restrict__ flag){
  int i = blockIdx.x*256 + threadIdx.x;
  if(i >= 2*256*768) return;
  int d = i / 196608, r = i % 196608;
  int k = r / 768, j = r % 768;
  out[i] = ldf(Wih, ((size_t)d*768 + j)*512 + k, *flag);
}

// ---------------- GEMM C = A@B, fp16 out. MODE 0: plain; MODE 1: clamp(exp2(v*2log2e)) ----
template<int MODE>
__global__ __launch_bounds__(256)
void k_gemm_h16(const float* __restrict__ A, int lda,
                const float* __restrict__ B, int ldb,
                u16* __restrict__ C, int N, int K)
{
  __shared__ float As[64][17];
  __shared__ float Bs[16][65];
  const int m0 = blockIdx.x * 64, n0 = blockIdx.y * 64;
  const int tid = threadIdx.x;
  const int arow = tid >> 2, acol = (tid & 3) * 4;
  const int brow = tid >> 4, bcol = (tid & 15) * 4;
  const int ty = tid >> 4, tx = tid & 15;
  float acc[4][4];
  #pragma unroll
  for(int i=0;i<4;++i)
    #pragma unroll
    for(int j=0;j<4;++j) acc[i][j] = 0.f;
  for(int k0 = 0; k0 < K; k0 += 16){
    float4 a4 = *(const float4*)(A + (size_t)(m0 + arow)*lda + k0 + acol);
    As[arow][acol+0] = a4.x; As[arow][acol+1] = a4.y;
    As[arow][acol+2] = a4.z; As[arow][acol+3] = a4.w;
    float4 b4 = *(const float4*)(B + (size_t)(k0 + brow)*ldb + n0 + bcol);
    Bs[brow][bcol+0] = b4.x; Bs[brow][bcol+1] = b4.y;
    Bs[brow][bcol+2] = b4.z; Bs[brow][bcol+3] = b4.w;
    __syncthreads();
    #pragma unroll
    for(int kk = 0; kk < 16; ++kk){
      float ar[4], br[4];
      #pragma unroll
      for(int i=0;i<4;++i) ar[i] = As[ty*4+i][kk];
      #pragma unroll
      for(int j=0;j<4;++j) br[j] = Bs[kk][tx*4+j];
      #pragma unroll
      for(int i=0;i<4;++i)
        #pragma unroll
        for(int j=0;j<4;++j) acc[i][j] = fmaf(ar[i], br[j], acc[i][j]);
    }
    __syncthreads();
  }
  #pragma unroll
  for(int i=0;i<4;++i)
    #pragma unroll
    for(int j=0;j<4;++j){
      float v = acc[i][j];
      if(MODE==1){ v = exp2fast(v * TWO_L2E); v = fminf(v, 65504.f); }
      C[(size_t)(m0 + ty*4 + i)*N + n0 + tx*4 + j] = f2h16(v);
    }
}

// ---------------- recurrent scan v5 ----------------
template<int USE_GIX>
__global__ __launch_bounds__(1024)
void k_scan5(const u16* __restrict__ E16,    // [2][16384][256] fp16 e^{2P} clamped
             const u16* __restrict__ qx16,   // [2][16384][256] fp16 x@Wi
             const u32* __restrict__ Wh2,    // [2][128][256]
             const u32* __restrict__ Wc2,    // [2][128][2304]
             const u32* __restrict__ xh2,    // [32][512][128] (variant B only)
             const u16* __restrict__ gix16,  // [2][16384][768] (variant A only)
             const u32* __restrict__ memh2,  // [32][512][128]
             const float* __restrict__ vf,
             const float* __restrict__ bihf,
             const float* __restrict__ bhhf,
             float* __restrict__ ys)         // [32][512][512] f32 = d_out
{
  __shared__ float h_l[256];
  __shared__ __align__(16) u32 h2[128];
  __shared__ __align__(16) u32 c2[128];
  __shared__ __align__(16) u32 x2[128];
  __shared__ __align__(16) float F[256];
  __shared__ __align__(16) float part[4096];
  __shared__ float ghgi[2304];
  __shared__ float esum_w[64];
  __shared__ float svp_sh;

  const int tid = threadIdx.x;
  const int p = blockIdx.x, d = p >> 5, b = p & 31;
  const int lane = tid & 63, wave = tid >> 6;
  const int g = lane >> 4, l = lane & 15;

  const u16* Eb   = E16  + ((size_t)d*16384 + (size_t)b*512)*256;
  const u16* qxb  = qx16 + ((size_t)d*16384 + (size_t)b*512)*256;
  const u32* Whd  = Wh2  + (size_t)d*128*256;
  const u32* Wcd  = Wc2  + (size_t)d*128*2304;
  const u32* xhb  = xh2  + (size_t)b*512*128;
  const u16* gixb = gix16 + ((size_t)d*16384 + (size_t)b*512)*768;
  const u32* mhb  = memh2 + (size_t)b*512*128;

  // prologue
  if(tid < 256){ h_l[tid] = 0.f; part[tid] = vf[d*256 + tid]; }
  if(tid < 128){
    h2[tid] = 0u;
    if(!USE_GIX){
      int tx0 = d ? 511 : 0;
      x2[tid] = xhb[(size_t)tx0*128 + tid];
    }
  }
  // per-lane v slice (16 a-values at l*16)
  float vr[16];
  {
    const float* vp = vf + d*256 + l*16;
    *(float4*)&vr[0]  = *(const float4*)(vp);
    *(float4*)&vr[4]  = *(const float4*)(vp + 4);
    *(float4*)&vr[8]  = *(const float4*)(vp + 8);
    *(float4*)&vr[12] = *(const float4*)(vp + 12);
  }
  float bh0=0,bh1=0,bh2v=0,bi0=0,bi1=0,bi2=0;
  if(tid < 256){
    bh0  = bhhf[d*768 + tid];       bi0 = bihf[d*768 + tid];
    bh1  = bhhf[d*768 + 256 + tid]; bi1 = bihf[d*768 + 256 + tid];
    bh2v = bhhf[d*768 + 512 + tid]; bi2 = bihf[d*768 + 512 + tid];
  }
  __syncthreads();
  if(tid == 0){ float s=0.f; for(int i=0;i<256;++i) s += part[i]; svp_sh = s * L2E; }
  __syncthreads();

  auto gdot = [&](int col, const u32* s2){
    const u32* wp = Wcd + col;
    float a0=0.f, a1=0.f, a2=0.f, a3=0.f;
    #pragma unroll 4
    for(int k0=0;k0<32;++k0){
      uint4 s4 = *(const uint4*)&s2[4*k0];
      a0 = fdot2f(wp[(size_t)(4*k0    )*2304], s4.x, a0);
      a1 = fdot2f(wp[(size_t)(4*k0 + 1)*2304], s4.y, a1);
      a2 = fdot2f(wp[(size_t)(4*k0 + 2)*2304], s4.z, a2);
      a3 = fdot2f(wp[(size_t)(4*k0 + 3)*2304], s4.w, a3);
    }
    ghgi[col] = (a0+a1)+(a2+a3);
  };

  for(int step = 0; step < 512; ++step){
    const int tx = d ? (511 - step) : step;

    // S0: R_Q — q partials (h@Wh). kq=tid>>8 (4 quarters of 32 k2)
    {
      const int a = tid & 255, kq = tid >> 8;
      const u32* wp = Whd + (size_t)(kq*32)*256 + a;
      float q0=0.f,q1=0.f,q2=0.f,q3=0.f;
      #pragma unroll
      for(int i0=0;i0<8;++i0){
        uint4 hv = *(const uint4*)&h2[kq*32 + 4*i0];
        q0 = fdot2f(wp[(size_t)(4*i0    )*256], hv.x, q0);
        q1 = fdot2f(wp[(size_t)(4*i0 + 1)*256], hv.y, q1);
        q2 = fdot2f(wp[(size_t)(4*i0 + 2)*256], hv.z, q2);
        q3 = fdot2f(wp[(size_t)(4*i0 + 3)*256], hv.w, q3);
      }
      part[kq*256 + a] = (q0+q1)+(q2+q3);
    }
    __syncthreads();
    // S1: F = e^{2q}
    if(tid < 256){
      float q = h16f(qxb[(size_t)tx*256 + tid])
              + part[tid] + part[256+tid] + part[512+tid] + part[768+tid];
      F[tid] = exp2fast(q * TWO_L2E);
    }
    __syncthreads();

    // S2: gemv h-cols (+x-cols in variant B) overlapped with R_A
    {
      if(tid < 768) gdot(tid, h2);
      if(!USE_GIX){
        if(tid >= 768) gdot(1536 + (tid - 768), x2);
        if(tid < 512)  gdot(1792 + tid, x2);
      }

      // R_A: group g owns row m = wave*32 + it*4 + g; lane-l owns a = l*16..l*16+15
      float Fr[16];
      {
        const float* fp = F + l*16;
        *(float4*)&Fr[0]  = *(const float4*)(fp);
        *(float4*)&Fr[4]  = *(const float4*)(fp + 4);
        *(float4*)&Fr[8]  = *(const float4*)(fp + 8);
        *(float4*)&Fr[12] = *(const float4*)(fp + 12);
      }
      float cr[16];
      #pragma unroll
      for(int i=0;i<16;++i) cr[i] = 0.f;
      float esum = 0.f;
      const float svp = svp_sh;

      #pragma unroll 2
      for(int it=0; it<8; ++it){
        const int m = wave*32 + it*4 + g;
        uint4 e0 = *(const uint4*)(Eb + (size_t)m*256 + l*16);
        uint4 e1 = *(const uint4*)(Eb + (size_t)m*256 + l*16 + 8);
        float u = 0.f;
        {
          u32 eu0=e0.x, eu1=e0.y, eu2=e0.z, eu3=e0.w;
          u32 eu4=e1.x, eu5=e1.y, eu6=e1.z, eu7=e1.w;
          #define RA_PAIR(EU, J) { \
            half2v hh = __builtin_bit_cast(half2v, EU); \
            float t0 = rcpfast(fmaf((float)hh[0], Fr[2*(J)],   1.f)); \
            float t1 = rcpfast(fmaf((float)hh[1], Fr[2*(J)+1], 1.f)); \
            u = fmaf(vr[2*(J)], t0, u); u = fmaf(vr[2*(J)+1], t1, u); }
          RA_PAIR(eu0,0) RA_PAIR(eu1,1) RA_PAIR(eu2,2) RA_PAIR(eu3,3)
          RA_PAIR(eu4,4) RA_PAIR(eu5,5) RA_PAIR(eu6,6) RA_PAIR(eu7,7)
          #undef RA_PAIR
        }
        u += __shfl_xor(u, 1, 64);
        u += __shfl_xor(u, 2, 64);
        u += __shfl_xor(u, 4, 64);
        u += __shfl_xor(u, 8, 64);
        float es = exp2fast(fmaf(u, -TWO_L2E, svp));
        esum += es;
        uint4 m0 = *(const uint4*)(mhb + (size_t)m*128 + l*8);
        uint4 m1 = *(const uint4*)(mhb + (size_t)m*128 + l*8 + 4);
        {
          u32 mu0=m0.x, mu1=m0.y, mu2=m0.z, mu3=m0.w;
          u32 mu4=m1.x, mu5=m1.y, mu6=m1.z, mu7=m1.w;
          #define RC_PAIR(MU, J) { \
            half2v hh = __builtin_bit_cast(half2v, MU); \
            cr[2*(J)]   = fmaf((float)hh[0], es, cr[2*(J)]); \
            cr[2*(J)+1] = fmaf((float)hh[1], es, cr[2*(J)+1]); }
          RC_PAIR(mu0,0) RC_PAIR(mu1,1) RC_PAIR(mu2,2) RC_PAIR(mu3,3)
          RC_PAIR(mu4,4) RC_PAIR(mu5,5) RC_PAIR(mu6,6) RC_PAIR(mu7,7)
          #undef RC_PAIR
        }
      }
      // reduce c-partials across the 4 groups
      #pragma unroll
      for(int i=0;i<16;++i){
        cr[i] += __shfl_xor(cr[i], 16, 64);
        cr[i] += __shfl_xor(cr[i], 32, 64);
      }
      if(lane < 16){
        float* pp = part + wave*256 + l*16;
        *(float4*)(pp)      = make_float4(cr[0],  cr[1],  cr[2],  cr[3]);
        *(float4*)(pp + 4)  = make_float4(cr[4],  cr[5],  cr[6],  cr[7]);
        *(float4*)(pp + 8)  = make_float4(cr[8],  cr[9],  cr[10], cr[11]);
        *(float4*)(pp + 12) = make_float4(cr[12], cr[13], cr[14], cr[15]);
      }
      if(l == 0) esum_w[wave*4 + g] = esum;
    }
    __syncthreads();

    // S3: combine c + pack c2 (tid<128, 2 columns each)
    if(tid < 128){
      float rs = 0.f;
      #pragma unroll
      for(int i2=0;i2<64;++i2) rs += esum_w[i2];
      rs = rcpfast(rs);
      float lo = 0.f, hi = 0.f;
      #pragma unroll
      for(int w=0; w<16; ++w){
        lo += part[w*256 + 2*tid];
        hi += part[w*256 + 2*tid + 1];
      }
      c2[tid] = pkh2(lo*rs, hi*rs);
    }
    __syncthreads();

    // S4: gemv c-cols (768)
    if(tid < 768) gdot(768 + tid, c2);
    __syncthreads();

    // S5: gates + h update
    if(tid < 256){
      const int j = tid;
      float hr  = ghgi[j]       + bh0;
      float hz  = ghgi[256 + j] + bh1;
      float hn  = ghgi[512 + j] + bh2v;
      float ir, iz, inn;
      if(USE_GIX){
        const u16* gxp = gixb + (size_t)tx*768;
        ir  = ghgi[768 + j]       + h16f(gxp[j])       + bi0;
        iz  = ghgi[768 + 256 + j] + h16f(gxp[256 + j]) + bi1;
        inn = ghgi[768 + 512 + j] + h16f(gxp[512 + j]) + bi2;
      } else {
        ir  = ghgi[1536 + j]       + ghgi[768 + j]       + bi0;
        iz  = ghgi[1536 + 256 + j] + ghgi[768 + 256 + j] + bi1;
        inn = ghgi[1536 + 512 + j] + ghgi[768 + 512 + j] + bi2;
      }
      float r = rcpfast(1.f + exp2fast(-(ir + hr) * L2E));
      float z = rcpfast(1.f + exp2fast(-(iz + hz) * L2E));
      float narg = inn + r*hn;
      float n = 1.f - 2.f*rcpfast(1.f + exp2fast(narg * TWO_L2E));
      float hnew = (1.f - z)*n + z*h_l[j];
      h_l[j] = hnew;
      ys[((size_t)b*512 + tx)*512 + d*256 + j] = hnew;
    }
    __syncthreads();

    // S6: pack h2 (+ next x2 in variant B)
    if(tid < 128){
      h2[tid] = pkh2(h_l[2*tid], h_l[2*tid + 1]);
    } else if(!USE_GIX && tid < 256 && step < 511){
      int t = tid - 128;
      int txn = d ? (511 - (step+1)) : (step+1);
      x2[t] = xhb[(size_t)txn*128 + t];
    }
    __syncthreads();
  }
}

// ---------------- final gate ----------------
__global__ void k_gate_h(const u16* __restrict__ G, float* __restrict__ ysb, int n4){
  int i = blockIdx.x*256 + threadIdx.x;
  if(i >= n4) return;
  ushort4 g = ((const ushort4*)G)[i];
  float4 y = ((const float4*)ysb)[i];
  float4 o;
  o.x = y.x * rcpfast(1.f + exp2fast(-h16f(g.x) * L2E));
  o.y = y.y * rcpfast(1.f + exp2fast(-h16f(g.y) * L2E));
  o.z = y.z * rcpfast(1.f + exp2fast(-h16f(g.z) * L2E));
  o.w = y.w * rcpfast(1.f + exp2fast(-h16f(g.w) * L2E));
  ((float4*)ysb)[i] = o;
}

// ---------------- host ----------------
extern "C" void kernel_launch(void* const* d_in, const int* in_sizes, int n_in,
                              void* d_out, int out_size, void* d_ws, size_t ws_size,
                              hipStream_t stream)
{
  int iIn=-1, iMem=-1, iW[3]={-1,-1,-1}, nW=0, iV=-1, iWih=-1, iWhh=-1,
      iBih=-1, iBhh=-1, iWg=-1;
  for(int i = 0; i < n_in; ++i){
    switch(in_sizes[i]){
      case 4194304: if(iIn < 0) iIn = i; else if(iMem < 0) iMem = i; break;
      case 131072:  if(nW < 3) iW[nW++] = i; break;
      case 512:     iV = i; break;
      case 786432:  iWih = i; break;
      case 393216:  iWhh = i; break;
      case 1536:    if(iBih < 0) iBih = i; else if(iBhh < 0) iBhh = i; break;
      case 262144:  iWg = i; break;
      default: break;
    }
  }
  bool ok = (iIn>=0 && iMem>=0 && nW==3 && iV>=0 && iWih>=0 && iWhh>=0 &&
             iBih>=0 && iBhh>=0 && iWg>=0);
  if(!ok){
    k_sentinelf<<<(out_size + 255)/256, 256, 0, stream>>>((float*)d_out, out_size, 42.0f);
    return;
  }

  char* ws = (char*)d_ws;
  size_t off = 0;
  auto alloc = [&](size_t bytes)->void*{
    void* pp = ws + off; off += (bytes + 255) & ~(size_t)255; return pp;
  };
  float* cxf   = (float*)alloc(4194304ull*4);     // 16.8 MB (G16 reuses after scan)
  float* cmemf = (float*)alloc(4194304ull*4);     // 16.8 MB
  u16*   E16   = (u16*)  alloc(2ull*16384*256*2); // 16.8 MB
  u16*   qx16  = (u16*)  alloc(2ull*16384*256*2); // 16.8 MB
  u32*   memh2 = (u32*)  alloc(32ull*512*128*4);  //  8.4 MB
  u32*   Wh2   = (u32*)  alloc(2ull*128*256*4);   //  0.26 MB
  u32*   Wc2   = (u32*)  alloc(2ull*128*2304*4);  //  2.36 MB
  float* Wmf   = (float*)alloc(131072ull*4);
  float* Wif   = (float*)alloc(131072ull*4);
  float* Wgf   = (float*)alloc(262144ull*4);
  float* cvf   = (float*)alloc(512ull*4);
  float* bihf  = (float*)alloc(1536ull*4);
  float* bhhf  = (float*)alloc(1536ull*4);
  int*   flag  = (int*)  alloc(256);
  // base ≈ 80.4 MB.  Variant A needs +51.9 MB (WihT + gix16); B needs +8.4 (xh2)
  size_t needA = (2ull*256*768*4 + 255 + 2ull*16384*768*2 + 255);
  bool useGix = (off + needA <= ws_size);
  float* WihT  = nullptr;
  u16*   gix16 = nullptr;
  u32*   xh2   = nullptr;
  if(useGix){
    WihT  = (float*)alloc(2ull*256*768*4);        //  1.57 MB
    gix16 = (u16*)  alloc(2ull*16384*768*2);      // 50.3 MB
  } else {
    xh2   = (u32*)  alloc(32ull*512*128*4);       //  8.4 MB
  }
  if(off > ws_size){
    k_sentinelf<<<(out_size + 255)/256, 256, 0, stream>>>((float*)d_out, out_size, 43.0f);
    return;
  }

  k_detect<<<1, 256, 0, stream>>>((const u16*)d_in[iIn], 65536, flag);

  auto conv = [&](const void* src, float* dst, int n){
    k_convf<<<(n + 255)/256, 256, 0, stream>>>(src, dst, n, flag);
  };
  conv(d_in[iIn],   cxf,   4194304);
  conv(d_in[iMem],  cmemf, 4194304);
  conv(d_in[iW[0]], Wmf,   131072);
  conv(d_in[iW[1]], Wif,   131072);
  conv(d_in[iV],    cvf,   512);
  conv(d_in[iBih],  bihf,  1536);
  conv(d_in[iBhh],  bhhf,  1536);
  conv(d_in[iWg],   Wgf,   262144);
  k_pack_wh2<<<(2*128*256 + 255)/256, 256, 0, stream>>>(d_in[iW[2]], Wh2, flag);
  k_pack_wc2<<<(2*128*2304 + 255)/256, 256, 0, stream>>>(d_in[iWhh], d_in[iWih], Wc2, flag);
  k_pack_h2<<<(2097152 + 255)/256, 256, 0, stream>>>(d_in[iMem], memh2, 2097152, flag);
  if(!useGix)
    k_pack_h2<<<(2097152 + 255)/256, 256, 0, stream>>>(d_in[iIn], xh2, 2097152, flag);
  else
    k_pack_wiht<<<(2*256*768 + 255)/256, 256, 0, stream>>>(d_in[iWih], WihT, flag);

  // E16 = clamp(e^{2·(mem@Wm)}) ; qx16 = fp16(x@Wi) ; gix16 = fp16(x@W_ihx^T)
  for(int dd = 0; dd < 2; ++dd){
    k_gemm_h16<1><<<dim3(256, 4), 256, 0, stream>>>(
        cmemf, 256, Wmf + (size_t)dd*65536, 256,
        E16 + (size_t)dd*16384*256, 256, 256);
    k_gemm_h16<0><<<dim3(256, 4), 256, 0, stream>>>(
        cxf, 256, Wif + (size_t)dd*65536, 256,
        qx16 + (size_t)dd*16384*256, 256, 256);
    if(useGix)
      k_gemm_h16<0><<<dim3(256, 12), 256, 0, stream>>>(
          cxf, 256, WihT + (size_t)dd*196608, 768,
          gix16 + (size_t)dd*16384*768, 768, 256);
  }

  if(useGix)
    k_scan5<1><<<64, 1024, 0, stream>>>(E16, qx16, Wh2, Wc2, nullptr, gix16, memh2,
                                        cvf, bihf, bhhf, (float*)d_out);
  else
    k_scan5<0><<<64, 1024, 0, stream>>>(E16, qx16, Wh2, Wc2, xh2, nullptr, memh2,
                                        cvf, bihf, bhhf, (float*)d_out);

  // G16 = fp16(ys@Wg) into cxf space; gate in place
  u16* G16 = (u16*)cxf;
  k_gemm_h16<0><<<dim3(256, 8), 256, 0, stream>>>(
      (const float*)d_out, 512, Wgf, 512, G16, 512, 512);
  k_gate_h<<<(8388608/4 + 255)/256, 256, 0, stream>>>(G16, (float*)d_out, 8388608/4);
}